// Round 7
// baseline (3693.621 us; speedup 1.0000x reference)
//
#include <hip/hip_runtime.h>
#include <math.h>

// SPINN forward, fp32 throughout (argmax trajectory sensitivity forbids bf16/f16).
// 2 launches/step, uniform 512-block grids:
//   A (k_gemm, 512 blk x 128 thr): fused GEMM [gates-x 12x16 || lstm5 8x40], 8x8 acc
//     (4 ds_read_b128 / 64 FMA -> LDS-pipe bound drops 15.4 -> ~10 us)
//   B (k_B, 512 blk = row x 4 j-slices): gather(12+hh) + LSTM + argmax + hh-GEMM
//     + track-GEMM + node + stack + next-X. hh/track read ORIGINAL row-major
//     W_hh/W_track with contiguous float4 row streams (4x fewer load instrs,
//     L1-line reuse) instead of column-stride repacked copies.

#define B_ 128
#define CAP 40
#define XW 1536   // X row: [buf_h 0:512 | s1_h 512:1024 | s2_h 1024:1536]
#define GSPLIT 12
#define LSPLIT 8
#define NSTEP 64

__device__ __forceinline__ float sigm(float x) { return 1.f / (1.f + expf(-x)); }

// ---------------- repack weights ----------------
// W1T[k][n], k in [0,1536): W_ih[n][k].                                        N=1024
// W2T[k][n], k in [0,1024): k<512 -> W_right[n][k] (s1h), else W_left[n][k-512] (s2h). N=2560
__global__ void k_repack(const float* __restrict__ W_ih,
                         const float* __restrict__ W_left, const float* __restrict__ W_right,
                         const float* __restrict__ b_ih, const float* __restrict__ b_hh,
                         float* __restrict__ W1T, float* __restrict__ W2T,
                         float* __restrict__ b1) {
    size_t idx = (size_t)blockIdx.x * 256 + threadIdx.x;
    const size_t n1 = 1536ull * 1024ull;   // 1,572,864
    const size_t n2 = 1024ull * 2560ull;   // 2,621,440
    if (idx < n1) {
        int k = (int)(idx >> 10), n = (int)(idx & 1023);
        W1T[idx] = W_ih[(size_t)n * 1536 + k];
    } else if (idx < n1 + n2) {
        size_t r = idx - n1;
        int k = (int)(r / 2560), n = (int)(r % 2560);
        W2T[r] = (k < 512) ? W_right[(size_t)n * 512 + k] : W_left[(size_t)n * 512 + (k - 512)];
    } else if (idx < n1 + n2 + 1024) {
        int i = (int)(idx - n1 - n2);
        b1[i] = b_ih[i] + b_hh[i];
    }
}

// ---------------- init state ----------------
__global__ void k_init(const float* __restrict__ buffers, float* __restrict__ stack,
                       float* __restrict__ X, float* __restrict__ tc,
                       float* __restrict__ hh,
                       int* __restrict__ sptr, int* __restrict__ blen) {
    int b = blockIdx.x, t = threadIdx.x;
    const float* b0 = buffers + (size_t)b * 40 * 1024;      // buffers[b][0]
    const float* btop = b0 + 39 * 1024;                     // buffers[b][39]
    float* stk = stack + (size_t)b * CAP * 1024;
    for (int j = t; j < 1024; j += 256) { stk[j] = b0[j]; stk[1024 + j] = b0[j]; }
    float* Xb = X + (size_t)b * XW;
    for (int j = t; j < 512; j += 256) {
        Xb[j] = btop[j]; Xb[512 + j] = b0[j]; Xb[1024 + j] = b0[j];
    }
    tc[b * 256 + t] = 0.f;
    for (int j = t; j < 1024; j += 256) hh[(size_t)b * 1024 + j] = 0.f;  // th0 = 0
    if (t == 0) { sptr[b] = 2; blen[b] = 40; }
}

// ---------------- A: fused tiled fp32 GEMM (gates-x || lstm5-sub), k-split partials --
// [0,192):  gates-x: ks=bid>>4 (12), n0=(bid&15)*64, K-chunk=[ks*128,+128), aoff=0
// [192,512): lstm5:  ks=tI/40  (8),  n0=(tI%40)*64,  K-chunk=[ks*128,+128), aoff=512
// 128 threads: tile 128x64, thread-grid 16(m)x8(n), acc 8x8 -> 4 ds_read_b128 / 64 FMA.
__global__ __launch_bounds__(128, 1) void k_gemm(const float* __restrict__ X,
                                                 const float* __restrict__ W1T,
                                                 const float* __restrict__ W2T,
                                                 float* __restrict__ gpart,
                                                 float* __restrict__ lpart) {
    __shared__ float As[32][132];
    __shared__ float Ws[32][68];
    const int bid = blockIdx.x;
    const float* WT; float* out; int N, n0, k0, aoff;
    if (bid < 192) {
        int ks = bid >> 4, nb = bid & 15;
        WT = W1T; out = gpart + (size_t)ks * 131072;
        N = 1024; n0 = nb * 64; k0 = ks * 128; aoff = 0;
    } else {
        int tI = bid - 192; int ks = tI / 40, nb = tI % 40;
        WT = W2T; out = lpart + (size_t)ks * 327680;
        N = 2560; n0 = nb * 64; k0 = ks * 128; aoff = 512;
    }
    const int tid = threadIdx.x;
    const int tm = tid >> 3;      // 0..15
    const int tn = tid & 7;       // 0..7

    float acc[8][8];
#pragma unroll
    for (int i = 0; i < 8; i++)
#pragma unroll
        for (int j = 0; j < 8; j++) acc[i][j] = 0.f;

    for (int ki = 0; ki < 128; ki += 32) {
        const int kb = k0 + ki;
        __syncthreads();
        {   // stage A: rows m and m+64, 16 floats each (8 float4/thread)
            int m = tid >> 1;
            int c8 = (tid & 1) * 16;
            const float4* s0 = (const float4*)(X + (size_t)m * XW + aoff + kb + c8);
            const float4* s1 = (const float4*)(X + (size_t)(m + 64) * XW + aoff + kb + c8);
#pragma unroll
            for (int j = 0; j < 4; j++) {
                float4 v = s0[j];
                int kk = c8 + j * 4;
                As[kk + 0][m] = v.x; As[kk + 1][m] = v.y; As[kk + 2][m] = v.z; As[kk + 3][m] = v.w;
            }
#pragma unroll
            for (int j = 0; j < 4; j++) {
                float4 v = s1[j];
                int kk = c8 + j * 4;
                As[kk + 0][m + 64] = v.x; As[kk + 1][m + 64] = v.y;
                As[kk + 2][m + 64] = v.z; As[kk + 3][m + 64] = v.w;
            }
        }
        {   // stage W: Ws[kk][c..c+15] = WT[kb+kk][n0+c..] (4 float4/thread)
            int kk = tid >> 2;
            int c = (tid & 3) * 16;
            const float4* src = (const float4*)(WT + (size_t)(kb + kk) * N + n0 + c);
            float4* dst = (float4*)(&Ws[kk][c]);
            dst[0] = src[0]; dst[1] = src[1]; dst[2] = src[2]; dst[3] = src[3];
        }
        __syncthreads();
#pragma unroll 4
        for (int kk = 0; kk < 32; kk++) {
            float a[8], w[8];
            *(float4*)&a[0] = *(const float4*)&As[kk][tm * 4];
            *(float4*)&a[4] = *(const float4*)&As[kk][64 + tm * 4];
            *(float4*)&w[0] = *(const float4*)&Ws[kk][tn * 4];
            *(float4*)&w[4] = *(const float4*)&Ws[kk][32 + tn * 4];
#pragma unroll
            for (int i = 0; i < 8; i++)
#pragma unroll
                for (int j = 0; j < 8; j++) acc[i][j] += a[i] * w[j];
        }
    }
    float* base = out + n0;
#pragma unroll
    for (int i = 0; i < 8; i++) {
        int m = (i < 4) ? (tm * 4 + i) : (64 + tm * 4 + (i - 4));
        float* p = base + (size_t)m * N;
        *(float4*)(p + tn * 4)      = make_float4(acc[i][0], acc[i][1], acc[i][2], acc[i][3]);
        *(float4*)(p + 32 + tn * 4) = make_float4(acc[i][4], acc[i][5], acc[i][6], acc[i][7]);
    }
}

// ---------------- B: LSTM + argmax + hh-GEMM + track-GEMM + node + stack + next-X ----
// grid 512 = 128 rows x 4 j-slices (q). All 4 q-blocks of a row redundantly compute the
// LSTM/logits/argmax (deterministic, identical); slice work is split by q.
__global__ __launch_bounds__(256) void k_B(const float* __restrict__ gpart,
                                           const float* __restrict__ lpart,
                                           const float* __restrict__ hh_in,
                                           float* __restrict__ hh_out,
                                           const float* __restrict__ b1,
                                           const float* __restrict__ b_left,
                                           const float* __restrict__ W_track,
                                           const float* __restrict__ W_hh,
                                           const float* __restrict__ W_trans,
                                           const float* __restrict__ b_trans,
                                           const float* __restrict__ buffers,
                                           float* __restrict__ stack,
                                           float* __restrict__ X,
                                           const float* __restrict__ tc_in,
                                           float* __restrict__ tc_out,
                                           const int* __restrict__ sp_in,
                                           int* __restrict__ sp_out,
                                           const int* __restrict__ bl_in,
                                           int* __restrict__ bl_out,
                                           float* __restrict__ out_s) {
    const int bid = blockIdx.x;
    const int b = bid >> 2, q = bid & 3;
    const int t = threadIdx.x;
    const int sp = sp_in[b], bl = bl_in[b];
    __shared__ float sh_th[256];
    __shared__ float redw[4][4];
    __shared__ float shg[5][128];

    // 1) gather gates partials (12 splits + hh lump) + LSTM cell
    const float* gp = gpart + (size_t)b * 1024;
    const float* hp = hh_in + (size_t)b * 1024;
    float gi = b1[t] + hp[t],             gf = b1[256 + t] + hp[256 + t];
    float gg = b1[512 + t] + hp[512 + t], go = b1[768 + t] + hp[768 + t];
#pragma unroll 4
    for (int kc = 0; kc < GSPLIT; kc++) {
        const float* p = gp + (size_t)kc * 131072;
        gi += p[t]; gf += p[256 + t]; gg += p[512 + t]; go += p[768 + t];
    }
    float tcv = tc_in[b * 256 + t];
    float tcn = sigm(gf) * tcv + sigm(gi) * tanhf(gg);
    float thn = sigm(go) * tanhf(tcn);
    if ((t >> 6) == q) tc_out[b * 256 + t] = tcn;
    sh_th[t] = thn;

    // 2) logits via wave shfl reduction + argmax (all threads identically)
    float v0 = thn * W_trans[t],       v1 = thn * W_trans[256 + t];
    float v2 = thn * W_trans[512 + t], v3 = thn * W_trans[768 + t];
#pragma unroll
    for (int off = 32; off > 0; off >>= 1) {
        v0 += __shfl_down(v0, off); v1 += __shfl_down(v1, off);
        v2 += __shfl_down(v2, off); v3 += __shfl_down(v3, off);
    }
    if ((t & 63) == 0) {
        int w = t >> 6;
        redw[w][0] = v0; redw[w][1] = v1; redw[w][2] = v2; redw[w][3] = v3;
    }
    __syncthreads();                       // redw + sh_th ready
    float lg0 = redw[0][0] + redw[1][0] + redw[2][0] + redw[3][0] + b_trans[0];
    float lg1 = redw[0][1] + redw[1][1] + redw[2][1] + redw[3][1] + b_trans[1];
    float lg2 = redw[0][2] + redw[1][2] + redw[2][2] + redw[3][2] + b_trans[2];
    float lg3 = redw[0][3] + redw[1][3] + redw[2][3] + redw[3][3] + b_trans[3];
    int tr = 0; float best = lg0;
    if (lg1 > best) { best = lg1; tr = 1; }
    if (lg2 > best) { best = lg2; tr = 2; }
    if (lg3 > best) { best = lg3; tr = 3; }
    const bool do_shift = (tr == 3) && (bl > 2);
    const bool do_red   = (tr == 2) && (sp > 3);
    const int spn = sp + (do_shift ? 1 : 0) - (do_red ? 1 : 0);
    const int bln = bl - (do_shift ? 1 : 0);
    if (q == 0 && t == 0) {
        out_s[b * 4 + 0] = lg0; out_s[b * 4 + 1] = lg1;
        out_s[b * 4 + 2] = lg2; out_s[b * 4 + 3] = lg3;
        sp_out[b] = spn; bl_out[b] = bln;
    }
    float* stk = stack + (size_t)b * CAP * 1024;

    // 3) hh-GEMM for NEXT step's gates: row-major W_hh, contiguous float4 row stream.
    //    Accumulator grouping (k mod 4) identical to the strided version.
    {
        const float* wh = W_hh + (size_t)(q * 256 + t) * 256;
        float h0 = 0, h1 = 0, h2 = 0, h3 = 0;
#pragma unroll 8
        for (int k = 0; k < 256; k += 4) {
            float4 w = *(const float4*)(wh + k);
            h0 += sh_th[k]     * w.x;
            h1 += sh_th[k + 1] * w.y;
            h2 += sh_th[k + 2] * w.z;
            h3 += sh_th[k + 3] * w.w;
        }
        hh_out[(size_t)b * 1024 + q * 256 + t] = (h0 + h1) + (h2 + h3);
    }

    // 4) reduce rows: lstm5 = sub-partials + b_left + W_track@th_new ; node.
    //    kh = t>>7: half-waves split the K range (128 each) and LSPLIT halves.
    //    W_track read row-major (original layout), 5 contiguous float4 row streams.
    const int jj = t & 127, kh = t >> 7, j = q * 128 + jj;
    float node_h = 0.f;
    float a, ii, f1, f2, oo;
    if (do_red) {
        if (kh == 0) {
            a  = b_left[j];        ii = b_left[512 + j]; f1 = b_left[1024 + j];
            f2 = b_left[1536 + j]; oo = b_left[2048 + j];
        } else { a = ii = f1 = f2 = oo = 0.f; }
        const float* lp = lpart + (size_t)b * 2560;
        const int half = LSPLIT >> 1;
        for (int kc = kh * half; kc < kh * half + half; kc++) {
            const float* p = lp + (size_t)kc * 327680;
            a += p[j]; ii += p[512 + j]; f1 += p[1024 + j]; f2 += p[1536 + j]; oo += p[2048 + j];
        }
        const int kb = kh * 128;
        const float* wa = W_track + (size_t)j * 256 + kb;
        const float* wi = W_track + (size_t)(512 + j) * 256 + kb;
        const float* w1 = W_track + (size_t)(1024 + j) * 256 + kb;
        const float* w2 = W_track + (size_t)(1536 + j) * 256 + kb;
        const float* wo = W_track + (size_t)(2048 + j) * 256 + kb;
        const float* ths = &sh_th[kb];
#pragma unroll 4
        for (int k = 0; k < 128; k += 4) {
            float t0 = ths[k], t1 = ths[k + 1], t2 = ths[k + 2], t3 = ths[k + 3];
            float4 w;
            w = *(const float4*)(wa + k); a  += t0 * w.x; a  += t1 * w.y; a  += t2 * w.z; a  += t3 * w.w;
            w = *(const float4*)(wi + k); ii += t0 * w.x; ii += t1 * w.y; ii += t2 * w.z; ii += t3 * w.w;
            w = *(const float4*)(w1 + k); f1 += t0 * w.x; f1 += t1 * w.y; f1 += t2 * w.z; f1 += t3 * w.w;
            w = *(const float4*)(w2 + k); f2 += t0 * w.x; f2 += t1 * w.y; f2 += t2 * w.z; f2 += t3 * w.w;
            w = *(const float4*)(wo + k); oo += t0 * w.x; oo += t1 * w.y; oo += t2 * w.z; oo += t3 * w.w;
        }
        if (kh == 1) {
            shg[0][jj] = a; shg[1][jj] = ii; shg[2][jj] = f1; shg[3][jj] = f2; shg[4][jj] = oo;
        }
    }
    __syncthreads();                       // do_red is block-uniform
    if (do_red && kh == 0) {
        a += shg[0][jj]; ii += shg[1][jj]; f1 += shg[2][jj];
        f2 += shg[3][jj]; oo += shg[4][jj];
        float s1c = stk[(size_t)(sp - 1) * 1024 + 512 + j];
        float s2c = stk[(size_t)(sp - 2) * 1024 + 512 + j];
        float c = tanhf(a) * sigm(ii) + sigm(f1) * s2c + sigm(f2) * s1c;
        float h = sigm(oo) * tanhf(c);
        stk[(size_t)(sp - 2) * 1024 + j] = h;          // own-slice addresses only
        stk[(size_t)(sp - 2) * 1024 + 512 + j] = c;
        node_h = h;
    }
    // 5) shift: push buf_top (slot sp untouched by any read this step)
    if (do_shift) {
        const float* bt = buffers + ((size_t)b * 40 + (bl - 1)) * 1024;
        const int idx = q * 256 + t;
        stk[(size_t)sp * 1024 + idx] = bt[idx];
    }
    // 6) build next X (slice j, kh==0 threads)
    float* Xb = X + (size_t)b * XW;
    if (kh == 0) {
        const float* btn = buffers + ((size_t)b * 40 + (bln - 1)) * 1024;
        Xb[j] = btn[j];                                 // buf_top' h
        float s1h;
        if (do_red)        s1h = node_h;                // just-built node (register)
        else if (do_shift) s1h = buffers[((size_t)b * 40 + (bl - 1)) * 1024 + j];
        else               s1h = stk[(size_t)(sp - 1) * 1024 + j];
        Xb[512 + j] = s1h;
        Xb[1024 + j] = stk[(size_t)(spn - 2) * 1024 + j];  // untouched slot in all 3 cases
    }
}

// ---------------- host ----------------
extern "C" void kernel_launch(void* const* d_in, const int* in_sizes, int n_in,
                              void* d_out, int out_size, void* d_ws, size_t ws_size,
                              hipStream_t stream) {
    const float* buffers = (const float*)d_in[0];
    const float* W_left  = (const float*)d_in[1];
    const float* b_left  = (const float*)d_in[2];
    const float* W_right = (const float*)d_in[3];
    const float* W_track = (const float*)d_in[4];
    const float* W_ih    = (const float*)d_in[5];
    const float* W_hh    = (const float*)d_in[6];
    const float* b_ih    = (const float*)d_in[7];
    const float* b_hh    = (const float*)d_in[8];
    const float* W_trans = (const float*)d_in[9];
    const float* b_trans = (const float*)d_in[10];
    float* out = (float*)d_out;

    float* ws = (float*)d_ws;
    size_t off = 0;
    float* W1T   = ws + off; off += 1536ull * 1024;             // 1,572,864
    float* W2T   = ws + off; off += 1024ull * 2560;             // 2,621,440
    float* b1    = ws + off; off += 1024;
    float* X     = ws + off; off += (size_t)B_ * XW;            //   196,608
    float* tc_a  = ws + off; off += (size_t)B_ * 256;
    float* tc_b  = ws + off; off += (size_t)B_ * 256;
    float* hh_a  = ws + off; off += (size_t)B_ * 1024;          //   131,072
    float* hh_b  = ws + off; off += (size_t)B_ * 1024;
    float* gpart = ws + off; off += (size_t)GSPLIT * 131072;    // 1,572,864
    float* lpart = ws + off; off += (size_t)LSPLIT * 327680;    // 2,621,440
    float* stack = ws + off; off += (size_t)B_ * CAP * 1024;    // 5,242,880
    int* sp_a = (int*)(ws + off); off += 128;
    int* sp_b = (int*)(ws + off); off += 128;
    int* bl_a = (int*)(ws + off); off += 128;
    int* bl_b = (int*)(ws + off); off += 128;

    {
        size_t total = 1536ull * 1024 + 1024ull * 2560 + 1024;
        int blocks = (int)((total + 255) / 256);
        k_repack<<<blocks, 256, 0, stream>>>(W_ih, W_left, W_right, b_ih, b_hh,
                                             W1T, W2T, b1);
        k_init<<<B_, 256, 0, stream>>>(buffers, stack, X, tc_a, hh_a, sp_a, bl_a);
    }

    for (int s = 0; s < NSTEP; s++) {
        k_gemm<<<512, 128, 0, stream>>>(X, W1T, W2T, gpart, lpart);
        const float* tci = (s & 1) ? tc_b : tc_a;  float* tco = (s & 1) ? tc_a : tc_b;
        const float* hhi = (s & 1) ? hh_b : hh_a;  float* hho = (s & 1) ? hh_a : hh_b;
        const int*   spi = (s & 1) ? sp_b : sp_a;  int*   spo = (s & 1) ? sp_a : sp_b;
        const int*   bli = (s & 1) ? bl_b : bl_a;  int*   blo = (s & 1) ? bl_a : bl_b;
        k_B<<<512, 256, 0, stream>>>(gpart, lpart, hhi, hho, b1, b_left, W_track, W_hh,
                                     W_trans, b_trans, buffers, stack, X, tci, tco,
                                     spi, spo, bli, blo, out + (size_t)s * B_ * 4);
    }
    (void)in_sizes; (void)n_in; (void)out_size; (void)ws_size;
}

// Round 8
// 3016.651 us; speedup vs baseline: 1.2244x; 1.2244x over previous
//
#include <hip/hip_runtime.h>
#include <math.h>

// SPINN forward, fp32 throughout (argmax trajectory sensitivity forbids bf16/f16).
// 2 launches/step, uniform 512-block grids:
//   A (k_gemm, 512 blk x 128 thr): fused GEMM [gates-x 12x16 || lstm5 8x40], 8x8 acc
//     (4 ds_read_b128 / 64 FMA -> LDS-pipe bound ~10.2 us vs 15.4 at 8x4)
//   B (k_B, 512 blk = row x 4 j-slices): gather(12+hh) + LSTM + argmax + hh-GEMM
//     + track-GEMM + node + stack + next-X. WhhT/W3T are COLUMN-MAJOR repacks so
//     wave reads are coalesced (lane index varies fastest along memory) — round-7's
//     row-major per-thread streams were 64-line-per-instr scattered (16.5->48 us).

#define B_ 128
#define CAP 40
#define XW 1536   // X row: [buf_h 0:512 | s1_h 512:1024 | s2_h 1024:1536]
#define GSPLIT 12
#define LSPLIT 8
#define NSTEP 64

__device__ __forceinline__ float sigm(float x) { return 1.f / (1.f + expf(-x)); }

// ---------------- repack weights ----------------
// W1T[k][n], k in [0,1536): W_ih[n][k].                                        N=1024
// W2T[k][n], k in [0,1024): k<512 -> W_right[n][k] (s1h), else W_left[n][k-512] (s2h). N=2560
// W3T[k][n], k in [0,256):  W_track[n][k].                                     N=2560
// WhhT[k][n], k in [0,256): W_hh[n][k].                                        N=1024
__global__ void k_repack(const float* __restrict__ W_ih, const float* __restrict__ W_hh,
                         const float* __restrict__ W_left, const float* __restrict__ W_right,
                         const float* __restrict__ W_track, const float* __restrict__ b_ih,
                         const float* __restrict__ b_hh,
                         float* __restrict__ W1T, float* __restrict__ W2T,
                         float* __restrict__ W3T, float* __restrict__ WhhT,
                         float* __restrict__ b1) {
    size_t idx = (size_t)blockIdx.x * 256 + threadIdx.x;
    const size_t n1 = 1536ull * 1024ull;   // 1,572,864
    const size_t n2 = 1024ull * 2560ull;   // 2,621,440
    const size_t n3 = 256ull * 2560ull;    //   655,360
    const size_t n4 = 256ull * 1024ull;    //   262,144
    if (idx < n1) {
        int k = (int)(idx >> 10), n = (int)(idx & 1023);
        W1T[idx] = W_ih[(size_t)n * 1536 + k];
    } else if (idx < n1 + n2) {
        size_t r = idx - n1;
        int k = (int)(r / 2560), n = (int)(r % 2560);
        W2T[r] = (k < 512) ? W_right[(size_t)n * 512 + k] : W_left[(size_t)n * 512 + (k - 512)];
    } else if (idx < n1 + n2 + n3) {
        size_t r = idx - n1 - n2;
        int k = (int)(r / 2560), n = (int)(r % 2560);
        W3T[r] = W_track[(size_t)n * 256 + k];
    } else if (idx < n1 + n2 + n3 + n4) {
        size_t r = idx - n1 - n2 - n3;
        int k = (int)(r >> 10), n = (int)(r & 1023);
        WhhT[r] = W_hh[(size_t)n * 256 + k];
    } else if (idx < n1 + n2 + n3 + n4 + 1024) {
        int i = (int)(idx - n1 - n2 - n3 - n4);
        b1[i] = b_ih[i] + b_hh[i];
    }
}

// ---------------- init state ----------------
__global__ void k_init(const float* __restrict__ buffers, float* __restrict__ stack,
                       float* __restrict__ X, float* __restrict__ tc,
                       float* __restrict__ hh,
                       int* __restrict__ sptr, int* __restrict__ blen) {
    int b = blockIdx.x, t = threadIdx.x;
    const float* b0 = buffers + (size_t)b * 40 * 1024;      // buffers[b][0]
    const float* btop = b0 + 39 * 1024;                     // buffers[b][39]
    float* stk = stack + (size_t)b * CAP * 1024;
    for (int j = t; j < 1024; j += 256) { stk[j] = b0[j]; stk[1024 + j] = b0[j]; }
    float* Xb = X + (size_t)b * XW;
    for (int j = t; j < 512; j += 256) {
        Xb[j] = btop[j]; Xb[512 + j] = b0[j]; Xb[1024 + j] = b0[j];
    }
    tc[b * 256 + t] = 0.f;
    for (int j = t; j < 1024; j += 256) hh[(size_t)b * 1024 + j] = 0.f;  // th0 = 0
    if (t == 0) { sptr[b] = 2; blen[b] = 40; }
}

// ---------------- A: fused tiled fp32 GEMM (gates-x || lstm5-sub), k-split partials --
// [0,192):  gates-x: ks=bid>>4 (12), n0=(bid&15)*64, K-chunk=[ks*128,+128), aoff=0
// [192,512): lstm5:  ks=tI/40  (8),  n0=(tI%40)*64,  K-chunk=[ks*128,+128), aoff=512
// 128 threads: tile 128x64, thread-grid 16(m)x8(n), acc 8x8 -> 4 ds_read_b128 / 64 FMA.
__global__ __launch_bounds__(128, 1) void k_gemm(const float* __restrict__ X,
                                                 const float* __restrict__ W1T,
                                                 const float* __restrict__ W2T,
                                                 float* __restrict__ gpart,
                                                 float* __restrict__ lpart) {
    __shared__ float As[32][132];
    __shared__ float Ws[32][68];
    const int bid = blockIdx.x;
    const float* WT; float* out; int N, n0, k0, aoff;
    if (bid < 192) {
        int ks = bid >> 4, nb = bid & 15;
        WT = W1T; out = gpart + (size_t)ks * 131072;
        N = 1024; n0 = nb * 64; k0 = ks * 128; aoff = 0;
    } else {
        int tI = bid - 192; int ks = tI / 40, nb = tI % 40;
        WT = W2T; out = lpart + (size_t)ks * 327680;
        N = 2560; n0 = nb * 64; k0 = ks * 128; aoff = 512;
    }
    const int tid = threadIdx.x;
    const int tm = tid >> 3;      // 0..15
    const int tn = tid & 7;       // 0..7

    float acc[8][8];
#pragma unroll
    for (int i = 0; i < 8; i++)
#pragma unroll
        for (int j = 0; j < 8; j++) acc[i][j] = 0.f;

    for (int ki = 0; ki < 128; ki += 32) {
        const int kb = k0 + ki;
        __syncthreads();
        {   // stage A: rows m and m+64, 16 floats each (8 float4/thread)
            int m = tid >> 1;
            int c8 = (tid & 1) * 16;
            const float4* s0 = (const float4*)(X + (size_t)m * XW + aoff + kb + c8);
            const float4* s1 = (const float4*)(X + (size_t)(m + 64) * XW + aoff + kb + c8);
#pragma unroll
            for (int j = 0; j < 4; j++) {
                float4 v = s0[j];
                int kk = c8 + j * 4;
                As[kk + 0][m] = v.x; As[kk + 1][m] = v.y; As[kk + 2][m] = v.z; As[kk + 3][m] = v.w;
            }
#pragma unroll
            for (int j = 0; j < 4; j++) {
                float4 v = s1[j];
                int kk = c8 + j * 4;
                As[kk + 0][m + 64] = v.x; As[kk + 1][m + 64] = v.y;
                As[kk + 2][m + 64] = v.z; As[kk + 3][m + 64] = v.w;
            }
        }
        {   // stage W: Ws[kk][c..c+15] = WT[kb+kk][n0+c..] (4 float4/thread)
            int kk = tid >> 2;
            int c = (tid & 3) * 16;
            const float4* src = (const float4*)(WT + (size_t)(kb + kk) * N + n0 + c);
            float4* dst = (float4*)(&Ws[kk][c]);
            dst[0] = src[0]; dst[1] = src[1]; dst[2] = src[2]; dst[3] = src[3];
        }
        __syncthreads();
#pragma unroll 4
        for (int kk = 0; kk < 32; kk++) {
            float a[8], w[8];
            *(float4*)&a[0] = *(const float4*)&As[kk][tm * 4];
            *(float4*)&a[4] = *(const float4*)&As[kk][64 + tm * 4];
            *(float4*)&w[0] = *(const float4*)&Ws[kk][tn * 4];
            *(float4*)&w[4] = *(const float4*)&Ws[kk][32 + tn * 4];
#pragma unroll
            for (int i = 0; i < 8; i++)
#pragma unroll
                for (int j = 0; j < 8; j++) acc[i][j] += a[i] * w[j];
        }
    }
    float* base = out + n0;
#pragma unroll
    for (int i = 0; i < 8; i++) {
        int m = (i < 4) ? (tm * 4 + i) : (64 + tm * 4 + (i - 4));
        float* p = base + (size_t)m * N;
        *(float4*)(p + tn * 4)      = make_float4(acc[i][0], acc[i][1], acc[i][2], acc[i][3]);
        *(float4*)(p + 32 + tn * 4) = make_float4(acc[i][4], acc[i][5], acc[i][6], acc[i][7]);
    }
}

// ---------------- B: LSTM + argmax + hh-GEMM + track-GEMM + node + stack + next-X ----
// grid 512 = 128 rows x 4 j-slices (q). All 4 q-blocks of a row redundantly compute the
// LSTM/logits/argmax (deterministic, identical); slice work is split by q.
__global__ __launch_bounds__(256) void k_B(const float* __restrict__ gpart,
                                           const float* __restrict__ lpart,
                                           const float* __restrict__ hh_in,
                                           float* __restrict__ hh_out,
                                           const float* __restrict__ b1,
                                           const float* __restrict__ b_left,
                                           const float* __restrict__ W3T,
                                           const float* __restrict__ WhhT,
                                           const float* __restrict__ W_trans,
                                           const float* __restrict__ b_trans,
                                           const float* __restrict__ buffers,
                                           float* __restrict__ stack,
                                           float* __restrict__ X,
                                           const float* __restrict__ tc_in,
                                           float* __restrict__ tc_out,
                                           const int* __restrict__ sp_in,
                                           int* __restrict__ sp_out,
                                           const int* __restrict__ bl_in,
                                           int* __restrict__ bl_out,
                                           float* __restrict__ out_s) {
    const int bid = blockIdx.x;
    const int b = bid >> 2, q = bid & 3;
    const int t = threadIdx.x;
    const int sp = sp_in[b], bl = bl_in[b];
    __shared__ float sh_th[256];
    __shared__ float redw[4][4];
    __shared__ float shg[5][128];

    // 1) gather gates partials (12 splits + hh lump) + LSTM cell
    const float* gp = gpart + (size_t)b * 1024;
    const float* hp = hh_in + (size_t)b * 1024;
    float gi = b1[t] + hp[t],             gf = b1[256 + t] + hp[256 + t];
    float gg = b1[512 + t] + hp[512 + t], go = b1[768 + t] + hp[768 + t];
#pragma unroll 4
    for (int kc = 0; kc < GSPLIT; kc++) {
        const float* p = gp + (size_t)kc * 131072;
        gi += p[t]; gf += p[256 + t]; gg += p[512 + t]; go += p[768 + t];
    }
    float tcv = tc_in[b * 256 + t];
    float tcn = sigm(gf) * tcv + sigm(gi) * tanhf(gg);
    float thn = sigm(go) * tanhf(tcn);
    if ((t >> 6) == q) tc_out[b * 256 + t] = tcn;
    sh_th[t] = thn;

    // 2) logits via wave shfl reduction + argmax (all threads identically)
    float v0 = thn * W_trans[t],       v1 = thn * W_trans[256 + t];
    float v2 = thn * W_trans[512 + t], v3 = thn * W_trans[768 + t];
#pragma unroll
    for (int off = 32; off > 0; off >>= 1) {
        v0 += __shfl_down(v0, off); v1 += __shfl_down(v1, off);
        v2 += __shfl_down(v2, off); v3 += __shfl_down(v3, off);
    }
    if ((t & 63) == 0) {
        int w = t >> 6;
        redw[w][0] = v0; redw[w][1] = v1; redw[w][2] = v2; redw[w][3] = v3;
    }
    __syncthreads();                       // redw + sh_th ready
    float lg0 = redw[0][0] + redw[1][0] + redw[2][0] + redw[3][0] + b_trans[0];
    float lg1 = redw[0][1] + redw[1][1] + redw[2][1] + redw[3][1] + b_trans[1];
    float lg2 = redw[0][2] + redw[1][2] + redw[2][2] + redw[3][2] + b_trans[2];
    float lg3 = redw[0][3] + redw[1][3] + redw[2][3] + redw[3][3] + b_trans[3];
    int tr = 0; float best = lg0;
    if (lg1 > best) { best = lg1; tr = 1; }
    if (lg2 > best) { best = lg2; tr = 2; }
    if (lg3 > best) { best = lg3; tr = 3; }
    const bool do_shift = (tr == 3) && (bl > 2);
    const bool do_red   = (tr == 2) && (sp > 3);
    const int spn = sp + (do_shift ? 1 : 0) - (do_red ? 1 : 0);
    const int bln = bl - (do_shift ? 1 : 0);
    if (q == 0 && t == 0) {
        out_s[b * 4 + 0] = lg0; out_s[b * 4 + 1] = lg1;
        out_s[b * 4 + 2] = lg2; out_s[b * 4 + 3] = lg3;
        sp_out[b] = spn; bl_out[b] = bln;
    }
    float* stk = stack + (size_t)b * CAP * 1024;

    // 3) hh-GEMM for NEXT step's gates: column-major WhhT, coalesced strided reads.
    {
        const float* wh = WhhT + q * 256 + t;
        float h0 = 0, h1 = 0, h2 = 0, h3 = 0;
#pragma unroll 8
        for (int k = 0; k < 256; k += 4) {
            h0 += sh_th[k]     * wh[(size_t)k * 1024];
            h1 += sh_th[k + 1] * wh[(size_t)(k + 1) * 1024];
            h2 += sh_th[k + 2] * wh[(size_t)(k + 2) * 1024];
            h3 += sh_th[k + 3] * wh[(size_t)(k + 3) * 1024];
        }
        hh_out[(size_t)b * 1024 + q * 256 + t] = (h0 + h1) + (h2 + h3);
    }

    // 4) reduce rows: lstm5 = sub-partials + b_left + W_track@th_new ; node.
    //    kh = t>>7: half-waves split the K range (128 each) and LSPLIT halves.
    //    W3T column-major: lane j varies fastest -> coalesced.
    const int jj = t & 127, kh = t >> 7, j = q * 128 + jj;
    float node_h = 0.f;
    float a, ii, f1, f2, oo;
    if (do_red) {
        if (kh == 0) {
            a  = b_left[j];        ii = b_left[512 + j]; f1 = b_left[1024 + j];
            f2 = b_left[1536 + j]; oo = b_left[2048 + j];
        } else { a = ii = f1 = f2 = oo = 0.f; }
        const float* lp = lpart + (size_t)b * 2560;
        const int half = LSPLIT >> 1;
        for (int kc = kh * half; kc < kh * half + half; kc++) {
            const float* p = lp + (size_t)kc * 327680;
            a += p[j]; ii += p[512 + j]; f1 += p[1024 + j]; f2 += p[1536 + j]; oo += p[2048 + j];
        }
        const float* w = W3T + j;
#pragma unroll 4
        for (int k = kh * 128; k < kh * 128 + 128; k++) {
            float th = sh_th[k];
            const float* wk = w + (size_t)k * 2560;
            a += th * wk[0]; ii += th * wk[512]; f1 += th * wk[1024];
            f2 += th * wk[1536]; oo += th * wk[2048];
        }
        if (kh == 1) {
            shg[0][jj] = a; shg[1][jj] = ii; shg[2][jj] = f1; shg[3][jj] = f2; shg[4][jj] = oo;
        }
    }
    __syncthreads();                       // do_red is block-uniform
    if (do_red && kh == 0) {
        a += shg[0][jj]; ii += shg[1][jj]; f1 += shg[2][jj];
        f2 += shg[3][jj]; oo += shg[4][jj];
        float s1c = stk[(size_t)(sp - 1) * 1024 + 512 + j];
        float s2c = stk[(size_t)(sp - 2) * 1024 + 512 + j];
        float c = tanhf(a) * sigm(ii) + sigm(f1) * s2c + sigm(f2) * s1c;
        float h = sigm(oo) * tanhf(c);
        stk[(size_t)(sp - 2) * 1024 + j] = h;          // own-slice addresses only
        stk[(size_t)(sp - 2) * 1024 + 512 + j] = c;
        node_h = h;
    }
    // 5) shift: push buf_top (slot sp untouched by any read this step)
    if (do_shift) {
        const float* bt = buffers + ((size_t)b * 40 + (bl - 1)) * 1024;
        const int idx = q * 256 + t;
        stk[(size_t)sp * 1024 + idx] = bt[idx];
    }
    // 6) build next X (slice j, kh==0 threads)
    float* Xb = X + (size_t)b * XW;
    if (kh == 0) {
        const float* btn = buffers + ((size_t)b * 40 + (bln - 1)) * 1024;
        Xb[j] = btn[j];                                 // buf_top' h
        float s1h;
        if (do_red)        s1h = node_h;                // just-built node (register)
        else if (do_shift) s1h = buffers[((size_t)b * 40 + (bl - 1)) * 1024 + j];
        else               s1h = stk[(size_t)(sp - 1) * 1024 + j];
        Xb[512 + j] = s1h;
        Xb[1024 + j] = stk[(size_t)(spn - 2) * 1024 + j];  // untouched slot in all 3 cases
    }
}

// ---------------- host ----------------
extern "C" void kernel_launch(void* const* d_in, const int* in_sizes, int n_in,
                              void* d_out, int out_size, void* d_ws, size_t ws_size,
                              hipStream_t stream) {
    const float* buffers = (const float*)d_in[0];
    const float* W_left  = (const float*)d_in[1];
    const float* b_left  = (const float*)d_in[2];
    const float* W_right = (const float*)d_in[3];
    const float* W_track = (const float*)d_in[4];
    const float* W_ih    = (const float*)d_in[5];
    const float* W_hh    = (const float*)d_in[6];
    const float* b_ih    = (const float*)d_in[7];
    const float* b_hh    = (const float*)d_in[8];
    const float* W_trans = (const float*)d_in[9];
    const float* b_trans = (const float*)d_in[10];
    float* out = (float*)d_out;

    float* ws = (float*)d_ws;
    size_t off = 0;
    float* W1T   = ws + off; off += 1536ull * 1024;             // 1,572,864
    float* W2T   = ws + off; off += 1024ull * 2560;             // 2,621,440
    float* W3T   = ws + off; off += 256ull * 2560;              //   655,360
    float* WhhT  = ws + off; off += 256ull * 1024;              //   262,144
    float* b1    = ws + off; off += 1024;
    float* X     = ws + off; off += (size_t)B_ * XW;            //   196,608
    float* tc_a  = ws + off; off += (size_t)B_ * 256;
    float* tc_b  = ws + off; off += (size_t)B_ * 256;
    float* hh_a  = ws + off; off += (size_t)B_ * 1024;          //   131,072
    float* hh_b  = ws + off; off += (size_t)B_ * 1024;
    float* gpart = ws + off; off += (size_t)GSPLIT * 131072;    // 1,572,864
    float* lpart = ws + off; off += (size_t)LSPLIT * 327680;    // 2,621,440
    float* stack = ws + off; off += (size_t)B_ * CAP * 1024;    // 5,242,880
    int* sp_a = (int*)(ws + off); off += 128;
    int* sp_b = (int*)(ws + off); off += 128;
    int* bl_a = (int*)(ws + off); off += 128;
    int* bl_b = (int*)(ws + off); off += 128;

    {
        size_t total = 1536ull * 1024 + 1024ull * 2560 + 256ull * 2560 + 256ull * 1024 + 1024;
        int blocks = (int)((total + 255) / 256);
        k_repack<<<blocks, 256, 0, stream>>>(W_ih, W_hh, W_left, W_right, W_track, b_ih, b_hh,
                                             W1T, W2T, W3T, WhhT, b1);
        k_init<<<B_, 256, 0, stream>>>(buffers, stack, X, tc_a, hh_a, sp_a, bl_a);
    }

    for (int s = 0; s < NSTEP; s++) {
        k_gemm<<<512, 128, 0, stream>>>(X, W1T, W2T, gpart, lpart);
        const float* tci = (s & 1) ? tc_b : tc_a;  float* tco = (s & 1) ? tc_a : tc_b;
        const float* hhi = (s & 1) ? hh_b : hh_a;  float* hho = (s & 1) ? hh_a : hh_b;
        const int*   spi = (s & 1) ? sp_b : sp_a;  int*   spo = (s & 1) ? sp_a : sp_b;
        const int*   bli = (s & 1) ? bl_b : bl_a;  int*   blo = (s & 1) ? bl_a : bl_b;
        k_B<<<512, 256, 0, stream>>>(gpart, lpart, hhi, hho, b1, b_left, W3T, WhhT,
                                     W_trans, b_trans, buffers, stack, X, tci, tco,
                                     spi, spo, bli, blo, out + (size_t)s * B_ * 4);
    }
    (void)in_sizes; (void)n_in; (void)out_size; (void)ws_size;
}

// Round 9
// 2884.735 us; speedup vs baseline: 1.2804x; 1.0457x over previous
//
#include <hip/hip_runtime.h>
#include <math.h>

// SPINN forward, fp32 throughout (argmax trajectory sensitivity forbids bf16/f16).
// 2 launches/step, uniform 512-block grids:
//   A (k_gemm, 512 blk x 256 thr):
//     mode 1: tile 128x128, acc 8x8, KS=64 (GSPLIT=24/LSPLIT=16) -> 0.5 B/FLOP LDS,
//             launch_bounds(256,2) so no VGPR cap spills (round-5's (256,3)=85-cap bug),
//             2 blocks/CU = 8 waves/CU (round-8 showed 4 waves/CU is fatal).
//     mode 0 (ws fallback): champion tile 128x64, acc 8x4, KS=128 (12/8).
//   B (k_B, 512 blk = row x 4 j-slices): gather + LSTM + argmax + hh-GEMM + track-GEMM
//     + node + stack + next-X. WhhT2/W3T2 are k-pair-interleaved ([k/2][n][2]) so the
//     GEMV loops use float2 loads: same bytes + bitwise-identical order, half the
//     load instructions.

#define B_ 128
#define CAP 40
#define XW 1536   // X row: [buf_h 0:512 | s1_h 512:1024 | s2_h 1024:1536]
#define NSTEP 64

__device__ __forceinline__ float sigm(float x) { return 1.f / (1.f + expf(-x)); }

// ---------------- repack weights ----------------
// W1T[k][n], k in [0,1536): W_ih[n][k].                               N=1024
// W2T[k][n], k in [0,1024): k<512 -> W_right[n][k], else W_left[n][k-512]. N=2560
// W3T2[k2][col][i] = W_track[col][2*k2+i]   (128 x 2560 x 2)
// WhhT2[k2][n][i]  = W_hh[n][2*k2+i]        (128 x 1024 x 2)
__global__ void k_repack(const float* __restrict__ W_ih, const float* __restrict__ W_hh,
                         const float* __restrict__ W_left, const float* __restrict__ W_right,
                         const float* __restrict__ W_track, const float* __restrict__ b_ih,
                         const float* __restrict__ b_hh,
                         float* __restrict__ W1T, float* __restrict__ W2T,
                         float* __restrict__ W3T2, float* __restrict__ WhhT2,
                         float* __restrict__ b1) {
    size_t idx = (size_t)blockIdx.x * 256 + threadIdx.x;
    const size_t n1 = 1536ull * 1024ull;   // 1,572,864
    const size_t n2 = 1024ull * 2560ull;   // 2,621,440
    const size_t n3 = 128ull * 2560ull * 2ull;  // 655,360
    const size_t n4 = 128ull * 1024ull * 2ull;  // 262,144
    if (idx < n1) {
        int k = (int)(idx >> 10), n = (int)(idx & 1023);
        W1T[idx] = W_ih[(size_t)n * 1536 + k];
    } else if (idx < n1 + n2) {
        size_t r = idx - n1;
        int k = (int)(r / 2560), n = (int)(r % 2560);
        W2T[r] = (k < 512) ? W_right[(size_t)n * 512 + k] : W_left[(size_t)n * 512 + (k - 512)];
    } else if (idx < n1 + n2 + n3) {
        size_t r = idx - n1 - n2;
        int k2 = (int)(r / 5120);
        int rem = (int)(r % 5120);
        int col = rem >> 1, i = rem & 1;
        W3T2[r] = W_track[(size_t)col * 256 + k2 * 2 + i];
    } else if (idx < n1 + n2 + n3 + n4) {
        size_t r = idx - n1 - n2 - n3;
        int k2 = (int)(r >> 11);
        int rem = (int)(r & 2047);
        int n = rem >> 1, i = rem & 1;
        WhhT2[r] = W_hh[(size_t)n * 256 + k2 * 2 + i];
    } else if (idx < n1 + n2 + n3 + n4 + 1024) {
        int i = (int)(idx - n1 - n2 - n3 - n4);
        b1[i] = b_ih[i] + b_hh[i];
    }
}

// ---------------- init state ----------------
__global__ void k_init(const float* __restrict__ buffers, float* __restrict__ stack,
                       float* __restrict__ X, float* __restrict__ tc,
                       float* __restrict__ hh,
                       int* __restrict__ sptr, int* __restrict__ blen) {
    int b = blockIdx.x, t = threadIdx.x;
    const float* b0 = buffers + (size_t)b * 40 * 1024;      // buffers[b][0]
    const float* btop = b0 + 39 * 1024;                     // buffers[b][39]
    float* stk = stack + (size_t)b * CAP * 1024;
    for (int j = t; j < 1024; j += 256) { stk[j] = b0[j]; stk[1024 + j] = b0[j]; }
    float* Xb = X + (size_t)b * XW;
    for (int j = t; j < 512; j += 256) {
        Xb[j] = btop[j]; Xb[512 + j] = b0[j]; Xb[1024 + j] = b0[j];
    }
    tc[b * 256 + t] = 0.f;
    for (int j = t; j < 1024; j += 256) hh[(size_t)b * 1024 + j] = 0.f;  // th0 = 0
    if (t == 0) { sptr[b] = 2; blen[b] = 40; }
}

// ---------------- A: fused tiled fp32 GEMM (gates-x || lstm5-sub), k-split partials --
// mode 1: [0,192): gates ks=bid>>3 (24, KS=64), n0=(bid&7)*128;
//         [192,512): lstm5 ks=tI/20 (16, KS=64), n0=(tI%20)*128. acc 8x8.
// mode 0: [0,192): gates ks=bid>>4 (12, KS=128), n0=(bid&15)*64;
//         [192,512): lstm5 ks=tI/40 (8, KS=128), n0=(tI%40)*64. acc 8x4 (champion).
__global__ __launch_bounds__(256, 2) void k_gemm(const float* __restrict__ X,
                                                 const float* __restrict__ W1T,
                                                 const float* __restrict__ W2T,
                                                 float* __restrict__ gpart,
                                                 float* __restrict__ lpart, int mode) {
    __shared__ float As[32][132];
    __shared__ float Ws[32][132];
    const int bid = blockIdx.x;
    const int tid = threadIdx.x;

    if (mode) {
        const float* WT; float* out; int N, n0, k0, aoff;
        if (bid < 192) {
            int ks = bid >> 3, nb = bid & 7;
            WT = W1T; out = gpart + (size_t)ks * 131072;
            N = 1024; n0 = nb * 128; k0 = ks * 64; aoff = 0;
        } else {
            int tI = bid - 192; int ks = tI / 20, nb = tI % 20;
            WT = W2T; out = lpart + (size_t)ks * 327680;
            N = 2560; n0 = nb * 128; k0 = ks * 64; aoff = 512;
        }
        const int tm = tid >> 4;      // 0..15
        const int tn = tid & 15;      // 0..15

        float acc[8][8];
#pragma unroll
        for (int i = 0; i < 8; i++)
#pragma unroll
            for (int j = 0; j < 8; j++) acc[i][j] = 0.f;

        for (int ki = 0; ki < 64; ki += 32) {
            const int kb = k0 + ki;
            __syncthreads();
            {   // stage A: As[kk][m] = X[m][aoff+kb+kk] ; 2 threads per row, 16 floats each
                int m = tid >> 1;
                int c8 = (tid & 1) * 16;
                const float4* src = (const float4*)(X + (size_t)m * XW + aoff + kb + c8);
#pragma unroll
                for (int j = 0; j < 4; j++) {
                    float4 v = src[j];
                    int kk = c8 + j * 4;
                    As[kk + 0][m] = v.x; As[kk + 1][m] = v.y; As[kk + 2][m] = v.z; As[kk + 3][m] = v.w;
                }
            }
            {   // stage W: Ws[kk][c..c+15] = WT[kb+kk][n0+c..] ; 8 threads per k-row
                int kk = tid >> 3;
                int c = (tid & 7) * 16;
                const float4* src = (const float4*)(WT + (size_t)(kb + kk) * N + n0 + c);
                float4* dst = (float4*)(&Ws[kk][c]);
                dst[0] = src[0]; dst[1] = src[1]; dst[2] = src[2]; dst[3] = src[3];
            }
            __syncthreads();
#pragma unroll 2
            for (int kk = 0; kk < 32; kk++) {
                float a[8], w[8];
                *(float4*)&a[0] = *(const float4*)&As[kk][tm * 4];
                *(float4*)&a[4] = *(const float4*)&As[kk][64 + tm * 4];
                *(float4*)&w[0] = *(const float4*)&Ws[kk][tn * 4];
                *(float4*)&w[4] = *(const float4*)&Ws[kk][64 + tn * 4];
#pragma unroll
                for (int i = 0; i < 8; i++)
#pragma unroll
                    for (int j = 0; j < 8; j++) acc[i][j] += a[i] * w[j];
            }
        }
        float* base = out + n0;
#pragma unroll
        for (int i = 0; i < 8; i++) {
            int m = (i < 4) ? (tm * 4 + i) : (64 + tm * 4 + (i - 4));
            float* p = base + (size_t)m * N;
            *(float4*)(p + tn * 4)      = make_float4(acc[i][0], acc[i][1], acc[i][2], acc[i][3]);
            *(float4*)(p + 64 + tn * 4) = make_float4(acc[i][4], acc[i][5], acc[i][6], acc[i][7]);
        }
    } else {
        const float* WT; float* out; int N, n0, k0, aoff;
        if (bid < 192) {
            int ks = bid >> 4, nb = bid & 15;
            WT = W1T; out = gpart + (size_t)ks * 131072;
            N = 1024; n0 = nb * 64; k0 = ks * 128; aoff = 0;
        } else {
            int tI = bid - 192; int ks = tI / 40, nb = tI % 40;
            WT = W2T; out = lpart + (size_t)ks * 327680;
            N = 2560; n0 = nb * 64; k0 = ks * 128; aoff = 512;
        }
        const int tm = tid >> 4, tn = tid & 15;
        float acc[8][4];
#pragma unroll
        for (int i = 0; i < 8; i++)
#pragma unroll
            for (int j = 0; j < 4; j++) acc[i][j] = 0.f;

        for (int ki = 0; ki < 128; ki += 32) {
            const int kb = k0 + ki;
            __syncthreads();
            {   int m = tid >> 1, c8 = (tid & 1) * 16;
                const float4* src = (const float4*)(X + (size_t)m * XW + aoff + kb + c8);
#pragma unroll
                for (int j = 0; j < 4; j++) {
                    float4 v = src[j];
                    int kk = c8 + j * 4;
                    As[kk + 0][m] = v.x; As[kk + 1][m] = v.y; As[kk + 2][m] = v.z; As[kk + 3][m] = v.w;
                }
            }
            {   int kk = tid >> 3, c = (tid & 7) * 8;
                const float4* src = (const float4*)(WT + (size_t)(kb + kk) * N + n0 + c);
                float4* dst = (float4*)(&Ws[kk][c]);
                dst[0] = src[0]; dst[1] = src[1];
            }
            __syncthreads();
#pragma unroll 4
            for (int kk = 0; kk < 32; kk++) {
                float a[8], w[4];
                *(float4*)&a[0] = *(const float4*)&As[kk][tm * 4];
                *(float4*)&a[4] = *(const float4*)&As[kk][64 + tm * 4];
                *(float4*)&w[0] = *(const float4*)&Ws[kk][tn * 4];
#pragma unroll
                for (int i = 0; i < 8; i++)
#pragma unroll
                    for (int j = 0; j < 4; j++) acc[i][j] += a[i] * w[j];
            }
        }
        float* base = out + n0 + tn * 4;
#pragma unroll
        for (int i = 0; i < 8; i++) {
            int m = (i < 4) ? (tm * 4 + i) : (64 + tm * 4 + (i - 4));
            *(float4*)(base + (size_t)m * N) = make_float4(acc[i][0], acc[i][1], acc[i][2], acc[i][3]);
        }
    }
}

// ---------------- B: LSTM + argmax + hh-GEMM + track-GEMM + node + stack + next-X ----
// grid 512 = 128 rows x 4 j-slices (q). All 4 q-blocks of a row redundantly compute the
// LSTM/logits/argmax (deterministic, identical); slice work is split by q.
__global__ __launch_bounds__(256) void k_B(const float* __restrict__ gpart,
                                           const float* __restrict__ lpart,
                                           const float* __restrict__ hh_in,
                                           float* __restrict__ hh_out,
                                           const float* __restrict__ b1,
                                           const float* __restrict__ b_left,
                                           const float* __restrict__ W3T2,
                                           const float* __restrict__ WhhT2,
                                           const float* __restrict__ W_trans,
                                           const float* __restrict__ b_trans,
                                           const float* __restrict__ buffers,
                                           float* __restrict__ stack,
                                           float* __restrict__ X,
                                           const float* __restrict__ tc_in,
                                           float* __restrict__ tc_out,
                                           const int* __restrict__ sp_in,
                                           int* __restrict__ sp_out,
                                           const int* __restrict__ bl_in,
                                           int* __restrict__ bl_out,
                                           float* __restrict__ out_s,
                                           int gsplit, int lsplit) {
    const int bid = blockIdx.x;
    const int b = bid >> 2, q = bid & 3;
    const int t = threadIdx.x;
    const int sp = sp_in[b], bl = bl_in[b];
    __shared__ float sh_th[256];
    __shared__ float redw[4][4];
    __shared__ float shg[5][128];

    // 1) gather gates partials (gsplit splits + hh lump) + LSTM cell
    const float* gp = gpart + (size_t)b * 1024;
    const float* hp = hh_in + (size_t)b * 1024;
    float gi = b1[t] + hp[t],             gf = b1[256 + t] + hp[256 + t];
    float gg = b1[512 + t] + hp[512 + t], go = b1[768 + t] + hp[768 + t];
#pragma unroll 4
    for (int kc = 0; kc < gsplit; kc++) {
        const float* p = gp + (size_t)kc * 131072;
        gi += p[t]; gf += p[256 + t]; gg += p[512 + t]; go += p[768 + t];
    }
    float tcv = tc_in[b * 256 + t];
    float tcn = sigm(gf) * tcv + sigm(gi) * tanhf(gg);
    float thn = sigm(go) * tanhf(tcn);
    if ((t >> 6) == q) tc_out[b * 256 + t] = tcn;
    sh_th[t] = thn;

    // 2) logits via wave shfl reduction + argmax (all threads identically)
    float v0 = thn * W_trans[t],       v1 = thn * W_trans[256 + t];
    float v2 = thn * W_trans[512 + t], v3 = thn * W_trans[768 + t];
#pragma unroll
    for (int off = 32; off > 0; off >>= 1) {
        v0 += __shfl_down(v0, off); v1 += __shfl_down(v1, off);
        v2 += __shfl_down(v2, off); v3 += __shfl_down(v3, off);
    }
    if ((t & 63) == 0) {
        int w = t >> 6;
        redw[w][0] = v0; redw[w][1] = v1; redw[w][2] = v2; redw[w][3] = v3;
    }
    __syncthreads();                       // redw + sh_th ready
    float lg0 = redw[0][0] + redw[1][0] + redw[2][0] + redw[3][0] + b_trans[0];
    float lg1 = redw[0][1] + redw[1][1] + redw[2][1] + redw[3][1] + b_trans[1];
    float lg2 = redw[0][2] + redw[1][2] + redw[2][2] + redw[3][2] + b_trans[2];
    float lg3 = redw[0][3] + redw[1][3] + redw[2][3] + redw[3][3] + b_trans[3];
    int tr = 0; float best = lg0;
    if (lg1 > best) { best = lg1; tr = 1; }
    if (lg2 > best) { best = lg2; tr = 2; }
    if (lg3 > best) { best = lg3; tr = 3; }
    const bool do_shift = (tr == 3) && (bl > 2);
    const bool do_red   = (tr == 2) && (sp > 3);
    const int spn = sp + (do_shift ? 1 : 0) - (do_red ? 1 : 0);
    const int bln = bl - (do_shift ? 1 : 0);
    if (q == 0 && t == 0) {
        out_s[b * 4 + 0] = lg0; out_s[b * 4 + 1] = lg1;
        out_s[b * 4 + 2] = lg2; out_s[b * 4 + 3] = lg3;
        sp_out[b] = spn; bl_out[b] = bln;
    }
    float* stk = stack + (size_t)b * CAP * 1024;

    // 3) hh-GEMM for NEXT step's gates: k-pair-interleaved WhhT2, float2 coalesced.
    //    Summation order identical to champion (k mod 4 grouping).
    {
        const float* wh = WhhT2 + (size_t)(q * 256 + t) * 2;
        float h0 = 0, h1 = 0, h2 = 0, h3 = 0;
#pragma unroll 8
        for (int k2 = 0; k2 < 128; k2 += 2) {
            float2 wA = *(const float2*)(wh + (size_t)k2 * 2048);
            float2 wB = *(const float2*)(wh + (size_t)(k2 + 1) * 2048);
            h0 += sh_th[2 * k2]     * wA.x;
            h1 += sh_th[2 * k2 + 1] * wA.y;
            h2 += sh_th[2 * k2 + 2] * wB.x;
            h3 += sh_th[2 * k2 + 3] * wB.y;
        }
        hh_out[(size_t)b * 1024 + q * 256 + t] = (h0 + h1) + (h2 + h3);
    }

    // 4) reduce rows: lstm5 = sub-partials + b_left + W_track@th_new ; node.
    //    kh = t>>7: half-waves split the K range (128 each) and lsplit halves.
    //    W3T2 k-pair-interleaved: float2 loads, same sequential-k order per accumulator.
    const int jj = t & 127, kh = t >> 7, j = q * 128 + jj;
    float node_h = 0.f;
    float a, ii, f1, f2, oo;
    if (do_red) {
        if (kh == 0) {
            a  = b_left[j];        ii = b_left[512 + j]; f1 = b_left[1024 + j];
            f2 = b_left[1536 + j]; oo = b_left[2048 + j];
        } else { a = ii = f1 = f2 = oo = 0.f; }
        const float* lp = lpart + (size_t)b * 2560;
        const int half = lsplit >> 1;
        for (int kc = kh * half; kc < kh * half + half; kc++) {
            const float* p = lp + (size_t)kc * 327680;
            a += p[j]; ii += p[512 + j]; f1 += p[1024 + j]; f2 += p[1536 + j]; oo += p[2048 + j];
        }
        const float* w = W3T2 + (size_t)j * 2;
#pragma unroll 4
        for (int k2 = kh * 64; k2 < kh * 64 + 64; k2++) {
            float t0 = sh_th[2 * k2], t1 = sh_th[2 * k2 + 1];
            const float* wk = w + (size_t)k2 * 5120;
            float2 wv;
            wv = *(const float2*)(wk);        a  += t0 * wv.x; a  += t1 * wv.y;
            wv = *(const float2*)(wk + 1024); ii += t0 * wv.x; ii += t1 * wv.y;
            wv = *(const float2*)(wk + 2048); f1 += t0 * wv.x; f1 += t1 * wv.y;
            wv = *(const float2*)(wk + 3072); f2 += t0 * wv.x; f2 += t1 * wv.y;
            wv = *(const float2*)(wk + 4096); oo += t0 * wv.x; oo += t1 * wv.y;
        }
        if (kh == 1) {
            shg[0][jj] = a; shg[1][jj] = ii; shg[2][jj] = f1; shg[3][jj] = f2; shg[4][jj] = oo;
        }
    }
    __syncthreads();                       // do_red is block-uniform
    if (do_red && kh == 0) {
        a += shg[0][jj]; ii += shg[1][jj]; f1 += shg[2][jj];
        f2 += shg[3][jj]; oo += shg[4][jj];
        float s1c = stk[(size_t)(sp - 1) * 1024 + 512 + j];
        float s2c = stk[(size_t)(sp - 2) * 1024 + 512 + j];
        float c = tanhf(a) * sigm(ii) + sigm(f1) * s2c + sigm(f2) * s1c;
        float h = sigm(oo) * tanhf(c);
        stk[(size_t)(sp - 2) * 1024 + j] = h;          // own-slice addresses only
        stk[(size_t)(sp - 2) * 1024 + 512 + j] = c;
        node_h = h;
    }
    // 5) shift: push buf_top (slot sp untouched by any read this step)
    if (do_shift) {
        const float* bt = buffers + ((size_t)b * 40 + (bl - 1)) * 1024;
        const int idx = q * 256 + t;
        stk[(size_t)sp * 1024 + idx] = bt[idx];
    }
    // 6) build next X (slice j, kh==0 threads)
    float* Xb = X + (size_t)b * XW;
    if (kh == 0) {
        const float* btn = buffers + ((size_t)b * 40 + (bln - 1)) * 1024;
        Xb[j] = btn[j];                                 // buf_top' h
        float s1h;
        if (do_red)        s1h = node_h;                // just-built node (register)
        else if (do_shift) s1h = buffers[((size_t)b * 40 + (bl - 1)) * 1024 + j];
        else               s1h = stk[(size_t)(sp - 1) * 1024 + j];
        Xb[512 + j] = s1h;
        Xb[1024 + j] = stk[(size_t)(spn - 2) * 1024 + j];  // untouched slot in all 3 cases
    }
}

// ---------------- host ----------------
extern "C" void kernel_launch(void* const* d_in, const int* in_sizes, int n_in,
                              void* d_out, int out_size, void* d_ws, size_t ws_size,
                              hipStream_t stream) {
    const float* buffers = (const float*)d_in[0];
    const float* W_left  = (const float*)d_in[1];
    const float* b_left  = (const float*)d_in[2];
    const float* W_right = (const float*)d_in[3];
    const float* W_track = (const float*)d_in[4];
    const float* W_ih    = (const float*)d_in[5];
    const float* W_hh    = (const float*)d_in[6];
    const float* b_ih    = (const float*)d_in[7];
    const float* b_hh    = (const float*)d_in[8];
    const float* W_trans = (const float*)d_in[9];
    const float* b_trans = (const float*)d_in[10];
    float* out = (float*)d_out;

    float* ws = (float*)d_ws;
    size_t off = 0;
    float* W1T   = ws + off; off += 1536ull * 1024;             // 1,572,864
    float* W2T   = ws + off; off += 1024ull * 2560;             // 2,621,440
    float* W3T2  = ws + off; off += 128ull * 2560 * 2;          //   655,360
    float* WhhT2 = ws + off; off += 128ull * 1024 * 2;          //   262,144
    float* b1    = ws + off; off += 1024;
    float* X     = ws + off; off += (size_t)B_ * XW;            //   196,608
    float* tc_a  = ws + off; off += (size_t)B_ * 256;
    float* tc_b  = ws + off; off += (size_t)B_ * 256;
    float* hh_a  = ws + off; off += (size_t)B_ * 1024;          //   131,072
    float* hh_b  = ws + off; off += (size_t)B_ * 1024;

    // mode 1 (128x128 tiles, KS=64, GSPLIT=24/LSPLIT=16) needs ~77.1 MB; gate on ws.
    size_t needA = (off + 24ull * 131072 + 16ull * 327680
                    + (size_t)B_ * CAP * 1024 + 512) * sizeof(float);
    const int mode   = (ws_size >= needA) ? 1 : 0;
    const int gsplit = mode ? 24 : 12;
    const int lsplit = mode ? 16 : 8;

    float* gpart = ws + off; off += (size_t)gsplit * 131072;
    float* lpart = ws + off; off += (size_t)lsplit * 327680;
    float* stack = ws + off; off += (size_t)B_ * CAP * 1024;    // 5,242,880
    int* sp_a = (int*)(ws + off); off += 128;
    int* sp_b = (int*)(ws + off); off += 128;
    int* bl_a = (int*)(ws + off); off += 128;
    int* bl_b = (int*)(ws + off); off += 128;

    {
        size_t total = 1536ull * 1024 + 1024ull * 2560 + 128ull * 2560 * 2
                     + 128ull * 1024 * 2 + 1024;
        int blocks = (int)((total + 255) / 256);
        k_repack<<<blocks, 256, 0, stream>>>(W_ih, W_hh, W_left, W_right, W_track, b_ih, b_hh,
                                             W1T, W2T, W3T2, WhhT2, b1);
        k_init<<<B_, 256, 0, stream>>>(buffers, stack, X, tc_a, hh_a, sp_a, bl_a);
    }

    for (int s = 0; s < NSTEP; s++) {
        k_gemm<<<512, 256, 0, stream>>>(X, W1T, W2T, gpart, lpart, mode);
        const float* tci = (s & 1) ? tc_b : tc_a;  float* tco = (s & 1) ? tc_a : tc_b;
        const float* hhi = (s & 1) ? hh_b : hh_a;  float* hho = (s & 1) ? hh_a : hh_b;
        const int*   spi = (s & 1) ? sp_b : sp_a;  int*   spo = (s & 1) ? sp_a : sp_b;
        const int*   bli = (s & 1) ? bl_b : bl_a;  int*   blo = (s & 1) ? bl_a : bl_b;
        k_B<<<512, 256, 0, stream>>>(gpart, lpart, hhi, hho, b1, b_left, W3T2, WhhT2,
                                     W_trans, b_trans, buffers, stack, X, tci, tco,
                                     spi, spo, bli, blo, out + (size_t)s * B_ * 4,
                                     gsplit, lsplit);
    }
    (void)in_sizes; (void)n_in; (void)out_size; (void)ws_size;
}